// Round 2
// baseline (494.482 us; speedup 1.0000x reference)
//
#include <hip/hip_runtime.h>

#define N_NODES 8192
#define IN_F 256
#define OUT_F 128
#define ALPHA 0.5f
#define JC 4
#define JCHUNK 2048            // N_NODES / JC
#define STEPS 64               // JCHUNK / 32

using short8 = __attribute__((ext_vector_type(8))) short;
using f32x4  = __attribute__((ext_vector_type(4))) float;

__device__ __forceinline__ unsigned short f2bf(float f){
  unsigned int u = __float_as_uint(f);
  u += 0x7fffu + ((u >> 16) & 1u);   // RNE
  return (unsigned short)(u >> 16);
}

// ---------------- K0: h = x @ W (fp32) ----------------
// grid 512 x 256 thr; block = 16 rows (2 blocks/CU, 8 waves/CU).
__global__ __launch_bounds__(256) void k_h(const float* __restrict__ x,
                                           const float* __restrict__ W,
                                           float* __restrict__ h){
  __shared__ float xs[16*IN_F];
  const int tid = threadIdx.x;
  const int r0 = blockIdx.x * 16;
  const float4* xg = (const float4*)(x + (size_t)r0*IN_F);
  float4* xl = (float4*)xs;
  #pragma unroll
  for(int i=0;i<4;i++) xl[tid + i*256] = xg[tid + i*256];
  __syncthreads();
  const int wave = tid >> 6, lane = tid & 63;
  float2 acc[4];
  #pragma unroll
  for(int j=0;j<4;j++){ acc[j].x = 0.f; acc[j].y = 0.f; }
  const float2* Wp = (const float2*)W;       // W[k][c] -> float2 idx k*64+lane
  for(int k4=0;k4<IN_F;k4+=4){
    float4 xq[4];
    #pragma unroll
    for(int j=0;j<4;j++) xq[j] = *(const float4*)&xs[(wave*4+j)*IN_F + k4];
    #pragma unroll
    for(int kk=0;kk<4;kk++){
      float2 wv = Wp[(size_t)(k4+kk)*64 + lane];
      #pragma unroll
      for(int j=0;j<4;j++){
        float xv = kk==0?xq[j].x : kk==1?xq[j].y : kk==2?xq[j].z : xq[j].w;
        acc[j].x += xv*wv.x; acc[j].y += xv*wv.y;
      }
    }
  }
  #pragma unroll
  for(int j=0;j<4;j++)
    *(float2*)(h + (size_t)(r0 + wave*4 + j)*OUT_F + lane*2) = acc[j];
}

// ---------------- K1: f1 = h@a1, f2 = h@a2 ----------------
__global__ __launch_bounds__(256) void k_f(const float* __restrict__ h,
                                           const float* __restrict__ a,
                                           float* __restrict__ f1,
                                           float* __restrict__ f2){
  const int wave = threadIdx.x >> 6, lane = threadIdx.x & 63;
  const int row = blockIdx.x*4 + wave;
  float2 hv = ((const float2*)(h + (size_t)row*OUT_F))[lane];
  float2 a1 = ((const float2*)a)[lane];
  float2 a2 = ((const float2*)(a + OUT_F))[lane];
  float s1 = hv.x*a1.x + hv.y*a1.y;
  float s2 = hv.x*a2.x + hv.y*a2.y;
  #pragma unroll
  for(int off=32; off; off>>=1){
    s1 += __shfl_down(s1, off);
    s2 += __shfl_down(s2, off);
  }
  if(lane == 0){ f1[row] = s1; f2[row] = s2; }
}

// ---------------- K2: pack h into MFMA-B fragment-major bf16 ----------------
// P element (kb, c, lane, t) = bf16(h[kb*32 + (lane>>4)*8 + t][c*16 + (lane&15)])
// flat short index: ((kb*8 + c)*64 + lane)*8 + t  -> each B-frag load is a
// contiguous 1KB (16B/lane) block. grid 256 (kb) x 256 thr.
#define LDW 132
__global__ __launch_bounds__(256) void k_pack(const float* __restrict__ h,
                                              unsigned short* __restrict__ P){
  __shared__ float ld[32*LDW];
  const int tid = threadIdx.x;
  const int kb = blockIdx.x, j0 = kb*32;
  #pragma unroll
  for(int i=0;i<4;i++){
    int idx = tid + i*256;            // 0..1023
    int row = idx >> 5, c4 = (idx & 31)*4;
    *(float4*)&ld[row*LDW + c4] = *(const float4*)(h + (size_t)(j0+row)*OUT_F + c4);
  }
  __syncthreads();
  #pragma unroll
  for(int i=0;i<2;i++){
    int o = tid*2 + i;                // 0..511
    int c = o >> 6, lane = o & 63;
    int q = lane >> 4, n = lane & 15;
    short8 v;
    #pragma unroll
    for(int t=0;t<8;t++) v[t] = (short)f2bf(ld[(q*8+t)*LDW + c*16 + n]);
    *(short8*)(P + ((size_t)(kb*8 + c)*64 + lane)*8) = v;
  }
}

// ---------------- K3: fused masked-exp + attn@h -> per-chunk partials ------
// Barrier-free, LDS-free, atomic-free. grid (JC, 128) x 256 thr.
// Each wave: 16 rows x 128 cols x 2048 k. A-frag (w values) computed directly
// in MFMA lane layout; B-frags are contiguous 1KB loads from P.
__global__ __launch_bounds__(256, 2) void k_attn(const int* __restrict__ adj,
    const unsigned short* __restrict__ P,
    const float* __restrict__ f1, const float* __restrict__ f2,
    float* __restrict__ part, float* __restrict__ denp){
  const int tid = threadIdx.x;
  const int wave = tid >> 6, lane = tid & 63;
  const int m = lane & 15, q = lane >> 4;
  const int jc = blockIdx.x;
  const int r0 = blockIdx.y*64 + wave*16;
  const int jbase = jc * JCHUNK;
  const int kb0 = jbase >> 5;
  const float rowf1 = f1[r0 + m];
  const int* ap = adj + (size_t)(r0 + m)*N_NODES + jbase + q*8;
  const float* f2p = f2 + jbase + q*8;
  const short8* Pv = (const short8*)P;

  f32x4 acc[8];
  #pragma unroll
  for(int c=0;c<8;c++) acc[c] = (f32x4){0,0,0,0};
  float den = 0.f;

  int4 a0 = *(const int4*)(ap);
  int4 a1 = *(const int4*)(ap + 4);

  #pragma unroll 2
  for(int s=0; s<STEPS; s++){
    int4 b0, b1;
    if(s+1 < STEPS){
      b0 = *(const int4*)(ap + (s+1)*32);
      b1 = *(const int4*)(ap + (s+1)*32 + 4);
    }
    float4 fa = *(const float4*)(f2p + s*32);
    float4 fb = *(const float4*)(f2p + s*32 + 4);
    short8 af;
    {
      float tv, ev, w;
      #define WELEM(slot, aval, f2v)                       \
        tv = rowf1 + (f2v);                                \
        ev = tv > 0.f ? tv : ALPHA*tv;                     \
        w  = __expf(ev);                                   \
        w  = ((aval) > 0) ? w : 0.f;                       \
        den += w;                                          \
        af[slot] = (short)f2bf(w);
      WELEM(0, a0.x, fa.x) WELEM(1, a0.y, fa.y)
      WELEM(2, a0.z, fa.z) WELEM(3, a0.w, fa.w)
      WELEM(4, a1.x, fb.x) WELEM(5, a1.y, fb.y)
      WELEM(6, a1.z, fb.z) WELEM(7, a1.w, fb.w)
      #undef WELEM
    }
    const short8* Bb = Pv + ((size_t)(kb0 + s)*512 + lane);
    #pragma unroll
    for(int c=0;c<8;c++)
      acc[c] = __builtin_amdgcn_mfma_f32_16x16x32_bf16(af, Bb[c*64], acc[c], 0,0,0);
    a0 = b0; a1 = b1;
  }

  // den: sum the 4 q-lanes of each row (lanes m, m+16, m+32, m+48)
  den += __shfl_down(den, 32);
  den += __shfl_down(den, 16);
  if(lane < 16) denp[(size_t)jc*N_NODES + r0 + lane] = den;

  // partials: C/D layout col=lane&15, row=q*4+reg (verified in prior round)
  float* pp = part + (size_t)jc*N_NODES*OUT_F;
  #pragma unroll
  for(int c=0;c<8;c++){
    #pragma unroll
    for(int reg=0;reg<4;reg++)
      pp[(size_t)(r0 + q*4 + reg)*OUT_F + c*16 + m] = acc[c][reg];
  }
}

// ---------------- K4: out = elu(sum(parts)/sum(dens)) ----------------
__global__ __launch_bounds__(256) void k_out(const float* __restrict__ part,
    const float* __restrict__ denp, float* __restrict__ out){
  const int idx = blockIdx.x*256 + threadIdx.x;
  const int r = idx >> 7;
  float v = 0.f, d = 0.f;
  #pragma unroll
  for(int p=0;p<JC;p++){
    v += part[(size_t)p*N_NODES*OUT_F + idx];
    d += denp[(size_t)p*N_NODES + r];
  }
  v /= d;
  out[idx] = v > 0.f ? v : (__expf(v) - 1.f);
}

extern "C" void kernel_launch(void* const* d_in, const int* in_sizes, int n_in,
                              void* d_out, int out_size, void* d_ws, size_t ws_size,
                              hipStream_t stream){
  const float* x   = (const float*)d_in[0];
  const int*   adj = (const int*)d_in[1];
  const float* W   = (const float*)d_in[2];
  const float* a   = (const float*)d_in[3];
  char* ws = (char*)d_ws;
  // ws: [0,4M) h | [4M,6M) P | [6M,+32K) f1 | [+32K,+64K) f2 |
  //     [8M,24M) parts (4 x 4MB) | [24M,+128K) dens
  float* h            = (float*)ws;
  unsigned short* P   = (unsigned short*)(ws + (4u<<20));
  float* f1           = (float*)(ws + (6u<<20));
  float* f2           = (float*)(ws + (6u<<20) + (32u<<10));
  float* part         = (float*)(ws + (8u<<20));
  float* denp         = (float*)(ws + (24u<<20));
  float* out          = (float*)d_out;

  k_h<<<512, 256, 0, stream>>>(x, W, h);
  k_f<<<2048, 256, 0, stream>>>(h, a, f1, f2);
  k_pack<<<256, 256, 0, stream>>>(h, P);
  k_attn<<<dim3(JC,128), 256, 0, stream>>>(adj, P, f1, f2, part, denp);
  k_out<<<(N_NODES*OUT_F)/256, 256, 0, stream>>>(part, denp, out);
}

// Round 3
// 458.317 us; speedup vs baseline: 1.0789x; 1.0789x over previous
//
#include <hip/hip_runtime.h>

#define N_NODES 8192
#define IN_F 256
#define OUT_F 128
#define ALPHA 0.5f
#define JC 8
#define KCHUNK 1024            // N_NODES / JC
#define ROUNDS 4               // LDS reloads per block (256 k each)
#define RSTEPS 8               // 32-k MFMA steps per round

using short8 = __attribute__((ext_vector_type(8))) short;
using f32x4  = __attribute__((ext_vector_type(4))) float;

__device__ __forceinline__ unsigned short f2bf(float f){
  unsigned int u = __float_as_uint(f);
  u += 0x7fffu + ((u >> 16) & 1u);   // RNE
  return (unsigned short)(u >> 16);
}

// ---------------- K0: h = x @ W (fp32) ----------------
__global__ __launch_bounds__(256) void k_h(const float* __restrict__ x,
                                           const float* __restrict__ W,
                                           float* __restrict__ h){
  __shared__ float xs[16*IN_F];
  const int tid = threadIdx.x;
  const int r0 = blockIdx.x * 16;
  const float4* xg = (const float4*)(x + (size_t)r0*IN_F);
  float4* xl = (float4*)xs;
  #pragma unroll
  for(int i=0;i<4;i++) xl[tid + i*256] = xg[tid + i*256];
  __syncthreads();
  const int wave = tid >> 6, lane = tid & 63;
  float2 acc[4];
  #pragma unroll
  for(int j=0;j<4;j++){ acc[j].x = 0.f; acc[j].y = 0.f; }
  const float2* Wp = (const float2*)W;
  for(int k4=0;k4<IN_F;k4+=4){
    float4 xq[4];
    #pragma unroll
    for(int j=0;j<4;j++) xq[j] = *(const float4*)&xs[(wave*4+j)*IN_F + k4];
    #pragma unroll
    for(int kk=0;kk<4;kk++){
      float2 wv = Wp[(size_t)(k4+kk)*64 + lane];
      #pragma unroll
      for(int j=0;j<4;j++){
        float xv = kk==0?xq[j].x : kk==1?xq[j].y : kk==2?xq[j].z : xq[j].w;
        acc[j].x += xv*wv.x; acc[j].y += xv*wv.y;
      }
    }
  }
  #pragma unroll
  for(int j=0;j<4;j++)
    *(float2*)(h + (size_t)(r0 + wave*4 + j)*OUT_F + lane*2) = acc[j];
}

// ---------------- K1: f1 = h@a1, f2 = h@a2 ----------------
__global__ __launch_bounds__(256) void k_f(const float* __restrict__ h,
                                           const float* __restrict__ a,
                                           float* __restrict__ f1,
                                           float* __restrict__ f2){
  const int wave = threadIdx.x >> 6, lane = threadIdx.x & 63;
  const int row = blockIdx.x*4 + wave;
  float2 hv = ((const float2*)(h + (size_t)row*OUT_F))[lane];
  float2 a1 = ((const float2*)a)[lane];
  float2 a2 = ((const float2*)(a + OUT_F))[lane];
  float s1 = hv.x*a1.x + hv.y*a1.y;
  float s2 = hv.x*a2.x + hv.y*a2.y;
  #pragma unroll
  for(int off=32; off; off>>=1){
    s1 += __shfl_down(s1, off);
    s2 += __shfl_down(s2, off);
  }
  if(lane == 0){ f1[row] = s1; f2[row] = s2; }
}

// ---------------- K2: pack h into MFMA-B fragment-major bf16 ----------------
// P short index ((kb*8 + c)*64 + lane)*8 + t = bf16(h[kb*32+(lane>>4)*8+t][c*16+(lane&15)])
#define LDW 132
__global__ __launch_bounds__(256) void k_pack(const float* __restrict__ h,
                                              unsigned short* __restrict__ P){
  __shared__ float ld[32*LDW];
  const int tid = threadIdx.x;
  const int kb = blockIdx.x, j0 = kb*32;
  #pragma unroll
  for(int i=0;i<4;i++){
    int idx = tid + i*256;
    int row = idx >> 5, c4 = (idx & 31)*4;
    *(float4*)&ld[row*LDW + c4] = *(const float4*)(h + (size_t)(j0+row)*OUT_F + c4);
  }
  __syncthreads();
  #pragma unroll
  for(int i=0;i<2;i++){
    int o = tid*2 + i;
    int c = o >> 6, lane = o & 63;
    int q = lane >> 4, n = lane & 15;
    short8 v;
    #pragma unroll
    for(int t=0;t<8;t++) v[t] = (short)f2bf(ld[(q*8+t)*LDW + c*16 + n]);
    *(short8*)(P + ((size_t)(kb*8 + c)*64 + lane)*8) = v;
  }
}

// ---------------- K3: fused masked-exp + attn@h -> per-chunk partials ------
// grid (JC=8, 64) x 256 thr. Block: 4 waves x 32 rows = 128 rows, K-chunk 1024.
// B held in LDS (64KB per round, 4 rounds) -> k-loop reads ONLY LDS + adj
// stream (1-step register prefetch). Immune to adj thrashing L2.
__global__ __launch_bounds__(256, 2) void k_attn(const int* __restrict__ adj,
    const unsigned short* __restrict__ P,
    const float* __restrict__ f1, const float* __restrict__ f2,
    float* __restrict__ part, float* __restrict__ denp){
  __shared__ __align__(16) short Blds[32768];   // 64 KB: [kb(8)][c(8)][lane(64)][t(8)]
  const int tid = threadIdx.x;
  const int wave = tid >> 6, lane = tid & 63;
  const int m = lane & 15, q = lane >> 4;
  const int jc = blockIdx.x;                    // blockId%8 == jc -> per-XCD jc locality
  const int rb = blockIdx.y;
  const int r0w = rb*128 + wave*32;
  const int kb0 = jc * (KCHUNK/32);             // global 32-k block base
  const float rf1a = f1[r0w + m];
  const float rf1b = f1[r0w + 16 + m];
  const int* ap0 = adj + (size_t)(r0w + m)*N_NODES + jc*KCHUNK + q*8;
  const int* ap1 = ap0 + (size_t)16*N_NODES;
  const float* f2p = f2 + jc*KCHUNK + q*8;
  const short8* Pv = (const short8*)P;

  f32x4 acc0[8], acc1[8];
  #pragma unroll
  for(int c=0;c<8;c++){ acc0[c] = (f32x4){0,0,0,0}; acc1[c] = (f32x4){0,0,0,0}; }
  float den0 = 0.f, den1 = 0.f;

  // adj prefetch: step 0
  int4 A00 = *(const int4*)(ap0);
  int4 A01 = *(const int4*)(ap0 + 4);
  int4 A10 = *(const int4*)(ap1);
  int4 A11 = *(const int4*)(ap1 + 4);

  auto welem8 = [&](const int4& a, const int4& b, const float4& fa,
                    const float4& fb, float rf1, float& den) -> short8 {
    short8 af; float tv, ev, w;
    #define WE(slot, av, fv)                               \
      tv = rf1 + (fv);                                     \
      ev = tv > 0.f ? tv : ALPHA*tv;                       \
      w  = __expf(ev);                                     \
      w  = ((av) > 0) ? w : 0.f;                           \
      den += w;                                            \
      af[slot] = (short)f2bf(w);
    WE(0,a.x,fa.x) WE(1,a.y,fa.y) WE(2,a.z,fa.z) WE(3,a.w,fa.w)
    WE(4,b.x,fb.x) WE(5,b.y,fb.y) WE(6,b.z,fb.z) WE(7,b.w,fb.w)
    #undef WE
    return af;
  };

  for(int rd=0; rd<ROUNDS; rd++){
    // ---- stage 64KB of fragment-major P into LDS ----
    const short8* Ps = Pv + (size_t)(kb0 + rd*8) * 512;   // 8 kb x 512 short8
    short8* Bl8 = (short8*)Blds;
    #pragma unroll
    for(int i=0;i<16;i++){
      int idx = i*256 + tid;
      Bl8[idx] = Ps[idx];
    }
    __syncthreads();
    for(int s=0; s<RSTEPS; s++){
      const int gs = rd*RSTEPS + s;                       // 0..31
      // prefetch adj for next step
      int4 B00=A00, B01=A01, B10=A10, B11=A11;
      if(gs+1 < ROUNDS*RSTEPS){
        B00 = *(const int4*)(ap0 + (gs+1)*32);
        B01 = *(const int4*)(ap0 + (gs+1)*32 + 4);
        B10 = *(const int4*)(ap1 + (gs+1)*32);
        B11 = *(const int4*)(ap1 + (gs+1)*32 + 4);
      }
      float4 fa = *(const float4*)(f2p + gs*32);
      float4 fb = *(const float4*)(f2p + gs*32 + 4);
      short8 af0 = welem8(A00, A01, fa, fb, rf1a, den0);
      short8 af1 = welem8(A10, A11, fa, fb, rf1b, den1);
      const short8* Bl = (const short8*)Blds + (s*512 + lane);
      #pragma unroll
      for(int c=0;c<8;c++){
        short8 Bf = Bl[c*64];
        acc0[c] = __builtin_amdgcn_mfma_f32_16x16x32_bf16(af0, Bf, acc0[c], 0,0,0);
        acc1[c] = __builtin_amdgcn_mfma_f32_16x16x32_bf16(af1, Bf, acc1[c], 0,0,0);
      }
      A00=B00; A01=B01; A10=B10; A11=B11;
    }
    __syncthreads();   // protect Blds before next round's staging
  }

  // den: lanes m,m+16,m+32,m+48 hold q-partials of row m
  den0 += __shfl_down(den0, 32); den0 += __shfl_down(den0, 16);
  den1 += __shfl_down(den1, 32); den1 += __shfl_down(den1, 16);
  if(lane < 16){
    denp[(size_t)jc*N_NODES + r0w + lane]      = den0;
    denp[(size_t)jc*N_NODES + r0w + 16 + lane] = den1;
  }
  // C/D layout: col = c*16 + m, row = q*4 + reg (verified)
  float* pp = part + (size_t)jc*N_NODES*OUT_F;
  #pragma unroll
  for(int c=0;c<8;c++){
    #pragma unroll
    for(int reg=0;reg<4;reg++){
      pp[(size_t)(r0w + q*4 + reg)*OUT_F      + c*16 + m] = acc0[c][reg];
      pp[(size_t)(r0w + 16 + q*4 + reg)*OUT_F + c*16 + m] = acc1[c][reg];
    }
  }
}

// ---------------- K4: out = elu(sum(parts)/sum(dens)) ----------------
__global__ __launch_bounds__(256) void k_out(const float* __restrict__ part,
    const float* __restrict__ denp, float* __restrict__ out){
  const int idx = blockIdx.x*256 + threadIdx.x;
  const int r = idx >> 7;
  float v = 0.f, d = 0.f;
  #pragma unroll
  for(int p=0;p<JC;p++){
    v += part[(size_t)p*N_NODES*OUT_F + idx];
    d += denp[(size_t)p*N_NODES + r];
  }
  v /= d;
  out[idx] = v > 0.f ? v : (__expf(v) - 1.f);
}

extern "C" void kernel_launch(void* const* d_in, const int* in_sizes, int n_in,
                              void* d_out, int out_size, void* d_ws, size_t ws_size,
                              hipStream_t stream){
  const float* x   = (const float*)d_in[0];
  const int*   adj = (const int*)d_in[1];
  const float* W   = (const float*)d_in[2];
  const float* a   = (const float*)d_in[3];
  char* ws = (char*)d_ws;
  // ws: [0,4M) h | [4M,6M) P | [6M,+32K) f1 | [+32K,+64K) f2 |
  //     [8M,40M) parts (8 x 4MB) | [40M,+256K) dens
  float* h            = (float*)ws;
  unsigned short* P   = (unsigned short*)(ws + (4u<<20));
  float* f1           = (float*)(ws + (6u<<20));
  float* f2           = (float*)(ws + (6u<<20) + (32u<<10));
  float* part         = (float*)(ws + (8u<<20));
  float* denp         = (float*)(ws + (40u<<20));
  float* out          = (float*)d_out;

  k_h<<<512, 256, 0, stream>>>(x, W, h);
  k_f<<<2048, 256, 0, stream>>>(h, a, f1, f2);
  k_pack<<<256, 256, 0, stream>>>(h, P);
  k_attn<<<dim3(JC,64), 256, 0, stream>>>(adj, P, f1, f2, part, denp);
  k_out<<<(N_NODES*OUT_F)/256, 256, 0, stream>>>(part, denp, out);
}

// Round 4
// 410.261 us; speedup vs baseline: 1.2053x; 1.1171x over previous
//
#include <hip/hip_runtime.h>

#define N_NODES 8192
#define IN_F 256
#define OUT_F 128
#define ALPHA 0.5f
#define JC 8
#define KCHUNK 1024            // N_NODES / JC
#define RK 128                 // k-window per round
#define ROUNDS 8               // KCHUNK / RK
#define RSTEPS 4               // 32-k MFMA steps per round

using short8 = __attribute__((ext_vector_type(8))) short;
using f32x4  = __attribute__((ext_vector_type(4))) float;

__device__ __forceinline__ unsigned int f2bf(float f){
  unsigned int u = __float_as_uint(f);
  u += 0x7fffu + ((u >> 16) & 1u);   // RNE
  return u >> 16;
}
__device__ __forceinline__ float bf2f(short s){
  return __uint_as_float(((unsigned int)(unsigned short)s) << 16);
}

// ---------------- K0: h = x @ W (fp32) ----------------
__global__ __launch_bounds__(256) void k_h(const float* __restrict__ x,
                                           const float* __restrict__ W,
                                           float* __restrict__ h){
  __shared__ float xs[16*IN_F];
  const int tid = threadIdx.x;
  const int r0 = blockIdx.x * 16;
  const float4* xg = (const float4*)(x + (size_t)r0*IN_F);
  float4* xl = (float4*)xs;
  #pragma unroll
  for(int i=0;i<4;i++) xl[tid + i*256] = xg[tid + i*256];
  __syncthreads();
  const int wave = tid >> 6, lane = tid & 63;
  float2 acc[4];
  #pragma unroll
  for(int j=0;j<4;j++){ acc[j].x = 0.f; acc[j].y = 0.f; }
  const float2* Wp = (const float2*)W;
  for(int k4=0;k4<IN_F;k4+=4){
    float4 xq[4];
    #pragma unroll
    for(int j=0;j<4;j++) xq[j] = *(const float4*)&xs[(wave*4+j)*IN_F + k4];
    #pragma unroll
    for(int kk=0;kk<4;kk++){
      float2 wv = Wp[(size_t)(k4+kk)*64 + lane];
      #pragma unroll
      for(int j=0;j<4;j++){
        float xv = kk==0?xq[j].x : kk==1?xq[j].y : kk==2?xq[j].z : xq[j].w;
        acc[j].x += xv*wv.x; acc[j].y += xv*wv.y;
      }
    }
  }
  #pragma unroll
  for(int j=0;j<4;j++)
    *(float2*)(h + (size_t)(r0 + wave*4 + j)*OUT_F + lane*2) = acc[j];
}

// ---------------- K1: f1 = h@a1, f2 = h@a2 ----------------
__global__ __launch_bounds__(256) void k_f(const float* __restrict__ h,
                                           const float* __restrict__ a,
                                           float* __restrict__ f1,
                                           float* __restrict__ f2){
  const int wave = threadIdx.x >> 6, lane = threadIdx.x & 63;
  const int row = blockIdx.x*4 + wave;
  float2 hv = ((const float2*)(h + (size_t)row*OUT_F))[lane];
  float2 a1 = ((const float2*)a)[lane];
  float2 a2 = ((const float2*)(a + OUT_F))[lane];
  float s1 = hv.x*a1.x + hv.y*a1.y;
  float s2 = hv.x*a2.x + hv.y*a2.y;
  #pragma unroll
  for(int off=32; off; off>>=1){
    s1 += __shfl_down(s1, off);
    s2 += __shfl_down(s2, off);
  }
  if(lane == 0){ f1[row] = s1; f2[row] = s2; }
}

// ---------------- K2: pack h into MFMA-B fragment-major bf16 ----------------
// P short idx ((kb*8+c)*64+lane)*8+t = bf16(h[kb*32+(lane>>4)*8+t][c*16+(lane&15)])
#define LDW 132
__global__ __launch_bounds__(256) void k_pack(const float* __restrict__ h,
                                              unsigned short* __restrict__ P){
  __shared__ float ld[32*LDW];
  const int tid = threadIdx.x;
  const int kb = blockIdx.x, j0 = kb*32;
  #pragma unroll
  for(int i=0;i<4;i++){
    int idx = tid + i*256;
    int row = idx >> 5, c4 = (idx & 31)*4;
    *(float4*)&ld[row*LDW + c4] = *(const float4*)(h + (size_t)(j0+row)*OUT_F + c4);
  }
  __syncthreads();
  #pragma unroll
  for(int i=0;i<2;i++){
    int o = tid*2 + i;
    int c = o >> 6, lane = o & 63;
    int q = lane >> 4, n = lane & 15;
    short8 v;
    #pragma unroll
    for(int t=0;t<8;t++) v[t] = (short)f2bf(ld[(q*8+t)*LDW + c*16 + n]);
    *(short8*)(P + ((size_t)(kb*8 + c)*64 + lane)*8) = v;
  }
}

// ---------------- K3: fused masked-exp + attn@h -> per-chunk partials ------
// grid (JC=8, 64) x 256 thr, 2 blocks/CU. Per round (128-k window):
//   staging: LINEAR adj reads (512B contiguous per wave-instr) -> w = mask*exp
//            computed inline -> bf16 -> XOR-swizzled LDS A-tile [128r x 128k];
//            B-tile (32KB) memcpy'd from fragment-major P (L2-resident per XCD).
//   mfma:    A-frags + B-frags from LDS only; den accumulated from A-frag bf16.
__global__ __launch_bounds__(256, 2) void k_attn(const int* __restrict__ adj,
    const unsigned short* __restrict__ P,
    const float* __restrict__ f1, const float* __restrict__ f2,
    float* __restrict__ part, float* __restrict__ denp){
  __shared__ __align__(16) unsigned short Alds[128*RK];  // 32 KB swizzled [row][k]
  __shared__ __align__(16) short Blds[RK*OUT_F];         // 32 KB fragment-major
  __shared__ float f1s[128];
  const int tid = threadIdx.x;
  const int wave = tid >> 6, lane = tid & 63;
  const int m = lane & 15, q = lane >> 4;
  const int jc = blockIdx.x;                 // == linear_block_id % 8 -> XCD-local
  const int r0b = blockIdx.y * 128;
  const int jb = jc * KCHUNK;
  const int kb0 = jc * (KCHUNK/32);
  // staging coords: thread covers rows {i*8+srow}, k-cols [sc0, sc0+4) of window
  const int srow = tid >> 5;                 // 0..7
  const int sc0  = (tid & 31) * 4;           // 0..124
  const int swz  = ((((sc0 >> 3) ^ srow) << 4) | ((sc0 & 4) << 1));  // byte offset in row

  if(tid < 128) f1s[tid] = f1[r0b + tid];

  f32x4 acc0[8], acc1[8];
  #pragma unroll
  for(int c=0;c<8;c++){ acc0[c] = (f32x4){0,0,0,0}; acc1[c] = (f32x4){0,0,0,0}; }
  float den0 = 0.f, den1 = 0.f;

  const char* Ab = (const char*)Alds;
  char* Aw = (char*)Alds + swz;
  const int mw = m & 7;                      // row&7 for both 16-row groups of this lane
  const int rg0 = wave*32 + m;

  __syncthreads();                           // f1s ready

  for(int rd=0; rd<ROUNDS; rd++){
    const int kbase = jb + rd*RK;
    // ---- B-tile: 32KB linear memcpy from P ----
    const int4* Pb = (const int4*)(P + ((size_t)(kb0 + rd*4) << 12));
    int4* Bl4 = (int4*)Blds;
    #pragma unroll
    for(int i=0;i<8;i++) Bl4[i*256 + tid] = Pb[i*256 + tid];
    // ---- A-tile: linear adj read -> w -> swizzled LDS ----
    float4 fv = *(const float4*)(f2 + kbase + sc0);   // hoisted: same for all i
    const char* ap = (const char*)adj + (((size_t)(r0b + srow)*N_NODES + kbase + sc0) << 2);
    #pragma unroll 4
    for(int i=0;i<16;i++){
      int4 av = *(const int4*)(ap + ((size_t)i*8*N_NODES << 2));
      float f1v = f1s[i*8 + srow];
      float t0 = f1v + fv.x, t1 = f1v + fv.y, t2 = f1v + fv.z, t3 = f1v + fv.w;
      t0 = t0 > 0.f ? t0 : ALPHA*t0;  t1 = t1 > 0.f ? t1 : ALPHA*t1;
      t2 = t2 > 0.f ? t2 : ALPHA*t2;  t3 = t3 > 0.f ? t3 : ALPHA*t3;
      float w0 = av.x > 0 ? __expf(t0) : 0.f;
      float w1 = av.y > 0 ? __expf(t1) : 0.f;
      float w2 = av.z > 0 ? __expf(t2) : 0.f;
      float w3 = av.w > 0 ? __expf(t3) : 0.f;
      uint2 pk;
      pk.x = f2bf(w0) | (f2bf(w1) << 16);
      pk.y = f2bf(w2) | (f2bf(w3) << 16);
      *(uint2*)(Aw + (i*8 + srow)*(RK*2)) = pk;
    }
    __syncthreads();
    // ---- MFMA phase: LDS only ----
    #pragma unroll
    for(int s=0;s<RSTEPS;s++){
      const int gq = ((s*4 + q) ^ mw) << 4;
      short8 A0 = *(const short8*)(Ab + rg0*(RK*2) + gq);
      short8 A1 = *(const short8*)(Ab + (rg0+16)*(RK*2) + gq);
      #pragma unroll
      for(int t=0;t<8;t++){ den0 += bf2f(A0[t]); den1 += bf2f(A1[t]); }
      const short8* Bl = (const short8*)Blds + s*512 + lane;
      #pragma unroll
      for(int c=0;c<8;c++){
        short8 Bf = Bl[c*64];
        acc0[c] = __builtin_amdgcn_mfma_f32_16x16x32_bf16(A0, Bf, acc0[c], 0,0,0);
        acc1[c] = __builtin_amdgcn_mfma_f32_16x16x32_bf16(A1, Bf, acc1[c], 0,0,0);
      }
    }
    __syncthreads();
  }

  // den: lanes m,m+16,m+32,m+48 hold q-partials of row m
  den0 += __shfl_down(den0, 32); den0 += __shfl_down(den0, 16);
  den1 += __shfl_down(den1, 32); den1 += __shfl_down(den1, 16);
  const int r0w = r0b + wave*32;
  if(lane < 16){
    denp[(size_t)jc*N_NODES + r0w + lane]      = den0;
    denp[(size_t)jc*N_NODES + r0w + 16 + lane] = den1;
  }
  // C/D layout: col = c*16 + m, row = q*4 + reg (verified)
  float* pp = part + (size_t)jc*N_NODES*OUT_F;
  #pragma unroll
  for(int c=0;c<8;c++){
    #pragma unroll
    for(int reg=0;reg<4;reg++){
      pp[(size_t)(r0w + q*4 + reg)*OUT_F      + c*16 + m] = acc0[c][reg];
      pp[(size_t)(r0w + 16 + q*4 + reg)*OUT_F + c*16 + m] = acc1[c][reg];
    }
  }
}

// ---------------- K4: out = elu(sum(parts)/sum(dens)) ----------------
__global__ __launch_bounds__(256) void k_out(const float* __restrict__ part,
    const float* __restrict__ denp, float* __restrict__ out){
  const int idx = blockIdx.x*256 + threadIdx.x;
  const int r = idx >> 7;
  float v = 0.f, d = 0.f;
  #pragma unroll
  for(int p=0;p<JC;p++){
    v += part[(size_t)p*N_NODES*OUT_F + idx];
    d += denp[(size_t)p*N_NODES + r];
  }
  v /= d;
  out[idx] = v > 0.f ? v : (__expf(v) - 1.f);
}

extern "C" void kernel_launch(void* const* d_in, const int* in_sizes, int n_in,
                              void* d_out, int out_size, void* d_ws, size_t ws_size,
                              hipStream_t stream){
  const float* x   = (const float*)d_in[0];
  const int*   adj = (const int*)d_in[1];
  const float* W   = (const float*)d_in[2];
  const float* a   = (const float*)d_in[3];
  char* ws = (char*)d_ws;
  float* h            = (float*)ws;
  unsigned short* P   = (unsigned short*)(ws + (4u<<20));
  float* f1           = (float*)(ws + (6u<<20));
  float* f2           = (float*)(ws + (6u<<20) + (32u<<10));
  float* part         = (float*)(ws + (8u<<20));
  float* denp         = (float*)(ws + (40u<<20));
  float* out          = (float*)d_out;

  k_h<<<512, 256, 0, stream>>>(x, W, h);
  k_f<<<2048, 256, 0, stream>>>(h, a, f1, f2);
  k_pack<<<256, 256, 0, stream>>>(h, P);
  k_attn<<<dim3(JC,64), 256, 0, stream>>>(adj, P, f1, f2, part, denp);
  k_out<<<(N_NODES*OUT_F)/256, 256, 0, stream>>>(part, denp, out);
}